// Round 1
// baseline (420.787 us; speedup 1.0000x reference)
//
#include <hip/hip_runtime.h>
#include <hip/hip_bf16.h>
#include <math.h>

// Pipeline: y = LN(x + gelu(Q(gelu(x@W1+b1)@W2+b2)@W3+b3)@W4+b4)
// Q = 8-qubit, 2-layer PennyLane-style circuit (RY(f) RZ RY RZ per wire + CNOT ring).
// Round 1: correctness-first fp32. GEMMs: 64x128 tile, BK=16, 4x8 microtile.
// Quantum: one block per batch row, state amplitude per thread, LDS exchange.

__device__ __forceinline__ float gelu_f(float x) {
    return 0.5f * x * (1.0f + erff(x * 0.70710678118654752f));
}

// ---------------------------------------------------------------------------
// Generic fp32 GEMM: C[M,N] = A[M,K] @ B[K,N] + bias (+ resid / gelu)
// MODE 0: C = gelu(A@B + bias)          (GEMM1: x@W1+b1)
// MODE 1: C = A@B + bias + resid        (GEMM4: e@W4+b4+x)
// BM=64, BN=128, BK=16, 256 threads, thread tile 4x8.
// Requires M%64==0, N%128==0, K%16==0 (holds: 16384, 256/768, 768/256).
// ---------------------------------------------------------------------------
template <int MODE>
__global__ __launch_bounds__(256) void gemm_kernel(
    const float* __restrict__ A, const float* __restrict__ B,
    const float* __restrict__ bias, const float* __restrict__ resid,
    float* __restrict__ C, int M, int N, int K)
{
    __shared__ float As[16][68];    // transposed A tile [k][m], +4 pad
    __shared__ float Bs[16][132];   // B tile [k][n], +4 pad

    const int tid = threadIdx.x;
    const int tx = tid & 15;        // col group (8 cols)
    const int ty = tid >> 4;        // row group (4 rows)
    const int br = blockIdx.y, bc = blockIdx.x;

    // staging indices
    const int arow = tid >> 2, acol = (tid & 3) << 2;   // A: 64 rows x 16 cols, 1 float4/thread
    const int brow = tid >> 4, bcol = (tid & 15) << 2;  // B: 16 rows x 128 cols, 2 float4/thread
    const float* Ap = A + (size_t)(br * 64 + arow) * K + acol;
    const float* Bp = B + (size_t)brow * N + bc * 128 + bcol;

    float acc[4][8];
    #pragma unroll
    for (int i = 0; i < 4; ++i)
        #pragma unroll
        for (int j = 0; j < 8; ++j) acc[i][j] = 0.0f;

    const int nk = K >> 4;
    for (int kt = 0; kt < nk; ++kt) {
        float4 av  = *(const float4*)(Ap + kt * 16);
        float4 bv0 = *(const float4*)(Bp + (size_t)kt * 16 * N);
        float4 bv1 = *(const float4*)(Bp + (size_t)kt * 16 * N + 64);
        As[acol + 0][arow] = av.x;
        As[acol + 1][arow] = av.y;
        As[acol + 2][arow] = av.z;
        As[acol + 3][arow] = av.w;
        *(float4*)&Bs[brow][bcol]      = bv0;
        *(float4*)&Bs[brow][bcol + 64] = bv1;
        __syncthreads();
        #pragma unroll
        for (int k = 0; k < 16; ++k) {
            float4 a  = *(const float4*)&As[k][ty << 2];
            float4 b0 = *(const float4*)&Bs[k][tx << 3];
            float4 b1 = *(const float4*)&Bs[k][(tx << 3) + 4];
            float ar[4] = {a.x, a.y, a.z, a.w};
            float brv[8] = {b0.x, b0.y, b0.z, b0.w, b1.x, b1.y, b1.z, b1.w};
            #pragma unroll
            for (int i = 0; i < 4; ++i)
                #pragma unroll
                for (int j = 0; j < 8; ++j)
                    acc[i][j] += ar[i] * brv[j];
        }
        __syncthreads();
    }

    const int row0 = br * 64 + (ty << 2);
    const int col0 = bc * 128 + (tx << 3);
    #pragma unroll
    for (int i = 0; i < 4; ++i) {
        float o[8];
        #pragma unroll
        for (int j = 0; j < 8; ++j) {
            float v = acc[i][j] + bias[col0 + j];
            if (MODE == 0) {
                v = gelu_f(v);
            } else {
                v += resid[(size_t)(row0 + i) * N + col0 + j];
            }
            o[j] = v;
        }
        *(float4*)&C[(size_t)(row0 + i) * N + col0]     = make_float4(o[0], o[1], o[2], o[3]);
        *(float4*)&C[(size_t)(row0 + i) * N + col0 + 4] = make_float4(o[4], o[5], o[6], o[7]);
    }
}

// ---------------------------------------------------------------------------
// Fused: feats = h_row@W2 + b2 ; z = quantum(feats) ; e = gelu(z@W3 + b3)
// One block (256 threads) per batch row. Thread t owns amplitude of state t.
// Wire w <-> bit (7-w) of the state index (PennyLane: wire 0 = MSB).
// ---------------------------------------------------------------------------
__global__ __launch_bounds__(256) void quantum_kernel(
    const float* __restrict__ h, const float* __restrict__ W2,
    const float* __restrict__ b2, const float* __restrict__ qw,
    const float* __restrict__ W3, const float* __restrict__ b3,
    float* __restrict__ e)
{
    __shared__ float exch[2][256][2];   // double-buffered (re,im) exchange
    __shared__ float sU[16][8];         // per (layer,wire) 2x2 complex U
    __shared__ float red[8][4];         // cross-wave reduction scratch
    __shared__ float sfz[8];            // feats, later z

    const int row = blockIdx.x;
    const int t = threadIdx.x;
    const int lane = t & 63, wid = t >> 6;

    // ---- feats = h_row @ W2 + b2  (8 block-wide dot products of length 256)
    const float hv = h[(size_t)row * 256 + t];
    #pragma unroll
    for (int w = 0; w < 8; ++w) {
        float v = hv * W2[t * 8 + w];
        #pragma unroll
        for (int off = 32; off > 0; off >>= 1) v += __shfl_down(v, off, 64);
        if (lane == 0) red[w][wid] = v;
    }
    __syncthreads();
    if (t < 8) sfz[t] = red[t][0] + red[t][1] + red[t][2] + red[t][3] + b2[t];
    __syncthreads();

    // ---- build U[l][w] = RZ(w2) RY(w1) RZ(w0) RY(feat_w)
    if (t < 16) {
        const int l = t >> 3, w = t & 7;
        const float w0 = qw[(l * 8 + w) * 3 + 0];
        const float w1 = qw[(l * 8 + w) * 3 + 1];
        const float w2 = qw[(l * 8 + w) * 3 + 2];
        const float a0 = 0.5f * w0, a2 = 0.5f * w2;
        float s1, c1; sincosf(0.5f * w1, &s1, &c1);
        float sp, cp; sincosf(a0 + a2, &sp, &cp);   // e^{-i(a0+a2)} = cp - i sp
        float sm, cm; sincosf(a0 - a2, &sm, &cm);   // e^{+i(a0-a2)} = cm + i sm
        const float C00r =  c1 * cp, C00i = -c1 * sp;
        const float C01r = -s1 * cm, C01i = -s1 * sm;
        const float C10r =  s1 * cm, C10i = -s1 * sm;
        const float C11r =  c1 * cp, C11i =  c1 * sp;
        float sf, cf; sincosf(0.5f * sfz[w], &sf, &cf);
        sU[t][0] =  cf * C00r + sf * C01r;   // U00
        sU[t][1] =  cf * C00i + sf * C01i;
        sU[t][2] = -sf * C00r + cf * C01r;   // U01
        sU[t][3] = -sf * C00i + cf * C01i;
        sU[t][4] =  cf * C10r + sf * C11r;   // U10
        sU[t][5] =  cf * C10i + sf * C11i;
        sU[t][6] = -sf * C10r + cf * C11r;   // U11
        sU[t][7] = -sf * C10i + cf * C11i;
    }
    __syncthreads();

    // ---- state-vector simulation
    float re = (t == 0) ? 1.0f : 0.0f;
    float im = 0.0f;
    int buf = 0;
    #pragma unroll
    for (int l = 0; l < 2; ++l) {
        #pragma unroll
        for (int w = 0; w < 8; ++w) {
            exch[buf][t][0] = re; exch[buf][t][1] = im;
            __syncthreads();
            const int k = 7 - w;
            const int p = t ^ (1 << k);
            const float ore = exch[buf][p][0], oim = exch[buf][p][1];
            const float* U = sU[l * 8 + w];
            const bool hi = (t >> k) & 1;
            // new = u0*me + u1*other  (u0 = diag entry, u1 = off-diag entry)
            const float u0r = hi ? U[6] : U[0];
            const float u0i = hi ? U[7] : U[1];
            const float u1r = hi ? U[4] : U[2];
            const float u1i = hi ? U[5] : U[3];
            const float nre = u0r * re - u0i * im + u1r * ore - u1i * oim;
            const float nim = u0r * im + u0i * re + u1r * oim + u1i * ore;
            re = nre; im = nim;
            buf ^= 1;
        }
        #pragma unroll
        for (int c = 0; c < 8; ++c) {
            exch[buf][t][0] = re; exch[buf][t][1] = im;
            __syncthreads();
            const int tw = (c + 1) & 7;
            const int kc = 7 - c, ktb = 7 - tw;
            const int src = ((t >> kc) & 1) ? (t ^ (1 << ktb)) : t;
            re = exch[buf][src][0]; im = exch[buf][src][1];
            buf ^= 1;
        }
    }

    // ---- z_w = sum_i |psi_i|^2 * (1 - 2*bit_{7-w}(i))
    const float prob = re * re + im * im;
    #pragma unroll
    for (int w = 0; w < 8; ++w) {
        float v = ((t >> (7 - w)) & 1) ? -prob : prob;
        #pragma unroll
        for (int off = 32; off > 0; off >>= 1) v += __shfl_down(v, off, 64);
        if (lane == 0) red[w][wid] = v;
    }
    __syncthreads();
    if (t < 8) sfz[t] = red[t][0] + red[t][1] + red[t][2] + red[t][3];
    __syncthreads();

    // ---- e = gelu(z @ W3 + b3)
    float acc = b3[t];
    #pragma unroll
    for (int q = 0; q < 8; ++q) acc += sfz[q] * W3[q * 256 + t];
    e[(size_t)row * 256 + t] = gelu_f(acc);
}

// ---------------------------------------------------------------------------
// In-place LayerNorm over last dim (768). One block per row.
// ---------------------------------------------------------------------------
__global__ __launch_bounds__(256) void ln_kernel(
    float* __restrict__ y, const float* __restrict__ gamma,
    const float* __restrict__ beta)
{
    __shared__ float red[2][4];
    __shared__ float stats[2];
    const int row = blockIdx.x, t = threadIdx.x;
    const int lane = t & 63, wid = t >> 6;
    float* yr = y + (size_t)row * 768;
    const float v0 = yr[t], v1 = yr[t + 256], v2 = yr[t + 512];
    float s = v0 + v1 + v2;
    float q = v0 * v0 + v1 * v1 + v2 * v2;
    #pragma unroll
    for (int off = 32; off > 0; off >>= 1) {
        s += __shfl_down(s, off, 64);
        q += __shfl_down(q, off, 64);
    }
    if (lane == 0) { red[0][wid] = s; red[1][wid] = q; }
    __syncthreads();
    if (t == 0) {
        const float S = red[0][0] + red[0][1] + red[0][2] + red[0][3];
        const float Q = red[1][0] + red[1][1] + red[1][2] + red[1][3];
        const float mu = S * (1.0f / 768.0f);
        const float var = Q * (1.0f / 768.0f) - mu * mu;
        stats[0] = mu;
        stats[1] = rsqrtf(var + 1e-5f);
    }
    __syncthreads();
    const float mu = stats[0], rstd = stats[1];
    yr[t]       = gamma[t]       * (v0 - mu) * rstd + beta[t];
    yr[t + 256] = gamma[t + 256] * (v1 - mu) * rstd + beta[t + 256];
    yr[t + 512] = gamma[t + 512] * (v2 - mu) * rstd + beta[t + 512];
}

extern "C" void kernel_launch(void* const* d_in, const int* in_sizes, int n_in,
                              void* d_out, int out_size, void* d_ws, size_t ws_size,
                              hipStream_t stream) {
    (void)n_in; (void)out_size; (void)ws_size;
    const float* x     = (const float*)d_in[0];
    const float* W1    = (const float*)d_in[1];
    const float* b1    = (const float*)d_in[2];
    const float* W2    = (const float*)d_in[3];
    const float* b2    = (const float*)d_in[4];
    const float* qw    = (const float*)d_in[5];
    const float* W3    = (const float*)d_in[6];
    const float* b3    = (const float*)d_in[7];
    const float* W4    = (const float*)d_in[8];
    const float* b4    = (const float*)d_in[9];
    const float* gamma = (const float*)d_in[10];
    const float* beta  = (const float*)d_in[11];
    float* out = (float*)d_out;

    const int D = 768, H = 256;
    const int B = in_sizes[0] / D;     // 16384
    float* h = (float*)d_ws;           // B x 256
    float* e = h + (size_t)B * H;      // B x 256

    dim3 blk(256);
    // GEMM1: h = gelu(x @ W1 + b1)      [B,768]@[768,256]
    gemm_kernel<0><<<dim3(H / 128, B / 64), blk, 0, stream>>>(x, W1, b1, nullptr, h, B, H, D);
    // feats -> quantum -> e
    quantum_kernel<<<dim3(B), blk, 0, stream>>>(h, W2, b2, qw, W3, b3, e);
    // GEMM4: out = e @ W4 + b4 + x      [B,256]@[256,768]
    gemm_kernel<1><<<dim3(D / 128, B / 64), blk, 0, stream>>>(e, W4, b4, x, out, B, D, H);
    // LayerNorm in-place on out
    ln_kernel<<<dim3(B), blk, 0, stream>>>(out, gamma, beta);
}

// Round 2
// 365.422 us; speedup vs baseline: 1.1515x; 1.1515x over previous
//
#include <hip/hip_runtime.h>
#include <hip/hip_bf16.h>
#include <math.h>

// Pipeline: y = LN(x + gelu(Q(gelu(x@W1+b1)@W2+b2)@W3+b3)@W4+b4)
// Round 2: quantum sim rewritten wave-local — one wave per batch row,
// 4 complex amplitudes per lane (state s = (lane<<2)|r), all exchange via
// __shfl_xor / register permutes. Zero __syncthreads, zero LDS in the sim.
// GEMMs/LN unchanged from round 1 (bf16-MFMA planned next).

__device__ __forceinline__ float gelu_f(float x) {
    return 0.5f * x * (1.0f + erff(x * 0.70710678118654752f));
}

// ---------------------------------------------------------------------------
// fp32 GEMM (unchanged): C[M,N] = A[M,K]@B[K,N] + bias (+gelu | +resid)
// ---------------------------------------------------------------------------
template <int MODE>
__global__ __launch_bounds__(256) void gemm_kernel(
    const float* __restrict__ A, const float* __restrict__ B,
    const float* __restrict__ bias, const float* __restrict__ resid,
    float* __restrict__ C, int M, int N, int K)
{
    __shared__ float As[16][68];
    __shared__ float Bs[16][132];

    const int tid = threadIdx.x;
    const int tx = tid & 15;
    const int ty = tid >> 4;
    const int br = blockIdx.y, bc = blockIdx.x;

    const int arow = tid >> 2, acol = (tid & 3) << 2;
    const int brow = tid >> 4, bcol = (tid & 15) << 2;
    const float* Ap = A + (size_t)(br * 64 + arow) * K + acol;
    const float* Bp = B + (size_t)brow * N + bc * 128 + bcol;

    float acc[4][8];
    #pragma unroll
    for (int i = 0; i < 4; ++i)
        #pragma unroll
        for (int j = 0; j < 8; ++j) acc[i][j] = 0.0f;

    const int nk = K >> 4;
    for (int kt = 0; kt < nk; ++kt) {
        float4 av  = *(const float4*)(Ap + kt * 16);
        float4 bv0 = *(const float4*)(Bp + (size_t)kt * 16 * N);
        float4 bv1 = *(const float4*)(Bp + (size_t)kt * 16 * N + 64);
        As[acol + 0][arow] = av.x;
        As[acol + 1][arow] = av.y;
        As[acol + 2][arow] = av.z;
        As[acol + 3][arow] = av.w;
        *(float4*)&Bs[brow][bcol]      = bv0;
        *(float4*)&Bs[brow][bcol + 64] = bv1;
        __syncthreads();
        #pragma unroll
        for (int k = 0; k < 16; ++k) {
            float4 a  = *(const float4*)&As[k][ty << 2];
            float4 b0 = *(const float4*)&Bs[k][tx << 3];
            float4 b1 = *(const float4*)&Bs[k][(tx << 3) + 4];
            float ar[4] = {a.x, a.y, a.z, a.w};
            float brv[8] = {b0.x, b0.y, b0.z, b0.w, b1.x, b1.y, b1.z, b1.w};
            #pragma unroll
            for (int i = 0; i < 4; ++i)
                #pragma unroll
                for (int j = 0; j < 8; ++j)
                    acc[i][j] += ar[i] * brv[j];
        }
        __syncthreads();
    }

    const int row0 = br * 64 + (ty << 2);
    const int col0 = bc * 128 + (tx << 3);
    #pragma unroll
    for (int i = 0; i < 4; ++i) {
        float o[8];
        #pragma unroll
        for (int j = 0; j < 8; ++j) {
            float v = acc[i][j] + bias[col0 + j];
            if (MODE == 0) {
                v = gelu_f(v);
            } else {
                v += resid[(size_t)(row0 + i) * N + col0 + j];
            }
            o[j] = v;
        }
        *(float4*)&C[(size_t)(row0 + i) * N + col0]     = make_float4(o[0], o[1], o[2], o[3]);
        *(float4*)&C[(size_t)(row0 + i) * N + col0 + 4] = make_float4(o[4], o[5], o[6], o[7]);
    }
}

// ---------------------------------------------------------------------------
// Wave-local fused: feats = h@W2+b2 ; z = quantum(feats) ; e = gelu(z@W3+b3)
// One WAVE (64 lanes) per batch row; 4 waves (4 rows) per 256-thread block.
// State index s = (lane << 2) | r :  bits 2..7 -> lane bits 0..5 (shfl_xor),
// bits 0..1 -> register index r (register permutes).
// Wire w acts on state bit k = 7-w  (PennyLane wire 0 = MSB).
// ---------------------------------------------------------------------------
__global__ __launch_bounds__(256) void quantum_kernel(
    const float* __restrict__ h, const float* __restrict__ W2,
    const float* __restrict__ b2, const float* __restrict__ qw,
    const float* __restrict__ W3, const float* __restrict__ b3,
    float* __restrict__ e)
{
    const int t = threadIdx.x;
    const int wid = t >> 6, L = t & 63;
    const int row = blockIdx.x * 4 + wid;

    // ---- feats = h_row @ W2 + b2 : lane owns h[4L..4L+3] and W2 rows 4L..4L+3
    const float4 hv = *(const float4*)(h + (size_t)row * 256 + L * 4);
    const float hr[4] = {hv.x, hv.y, hv.z, hv.w};
    float f[8];
    #pragma unroll
    for (int w = 0; w < 8; ++w) f[w] = 0.0f;
    #pragma unroll
    for (int r = 0; r < 4; ++r) {
        const float4 wa = *(const float4*)(W2 + (size_t)(4 * L + r) * 8);
        const float4 wb = *(const float4*)(W2 + (size_t)(4 * L + r) * 8 + 4);
        f[0] += hr[r] * wa.x; f[1] += hr[r] * wa.y;
        f[2] += hr[r] * wa.z; f[3] += hr[r] * wa.w;
        f[4] += hr[r] * wb.x; f[5] += hr[r] * wb.y;
        f[6] += hr[r] * wb.z; f[7] += hr[r] * wb.w;
    }
    #pragma unroll
    for (int w = 0; w < 8; ++w) {
        #pragma unroll
        for (int off = 1; off < 64; off <<= 1) f[w] += __shfl_xor(f[w], off, 64);
        f[w] += b2[w];
    }

    // per-wire RY(feat) terms (same value in all lanes)
    float cf[8], sf[8];
    #pragma unroll
    for (int w = 0; w < 8; ++w) sincosf(0.5f * f[w], &sf[w], &cf[w]);

    // ---- C[g] = RZ(w2) RY(w1) RZ(w0) for g = layer*8+wire; lane g holds C[g]
    float cc[8];
    {
        const int g = L & 15;
        const float w0 = qw[g * 3 + 0];
        const float w1 = qw[g * 3 + 1];
        const float w2 = qw[g * 3 + 2];
        const float a0 = 0.5f * w0, a2 = 0.5f * w2;
        float s1, c1; sincosf(0.5f * w1, &s1, &c1);
        float sp, cp; sincosf(a0 + a2, &sp, &cp);   // e^{-i(a0+a2)} = cp - i sp
        float sm, cm; sincosf(a0 - a2, &sm, &cm);   // e^{+i(a0-a2)} = cm + i sm
        cc[0] =  c1 * cp;  cc[1] = -c1 * sp;   // C00
        cc[2] = -s1 * cm;  cc[3] = -s1 * sm;   // C01
        cc[4] =  s1 * cm;  cc[5] = -s1 * sm;   // C10
        cc[6] =  c1 * cp;  cc[7] =  c1 * sp;   // C11
    }

    // ---- state: s = (L<<2)|r
    float re[4], im[4];
    #pragma unroll
    for (int r = 0; r < 4; ++r) { re[r] = 0.0f; im[r] = 0.0f; }
    re[0] = (L == 0) ? 1.0f : 0.0f;

    #pragma unroll
    for (int l = 0; l < 2; ++l) {
        // -------- single-qubit gates, wires 0..7 (state bit k = 7-w)
        #pragma unroll
        for (int w = 0; w < 8; ++w) {
            const int g = l * 8 + w;
            const float c0 = __shfl(cc[0], g, 64), c1 = __shfl(cc[1], g, 64);
            const float c2 = __shfl(cc[2], g, 64), c3 = __shfl(cc[3], g, 64);
            const float c4 = __shfl(cc[4], g, 64), c5 = __shfl(cc[5], g, 64);
            const float c6 = __shfl(cc[6], g, 64), c7 = __shfl(cc[7], g, 64);
            // U = C @ RY(f_w)
            const float U00r = cf[w]*c0 + sf[w]*c2, U00i = cf[w]*c1 + sf[w]*c3;
            const float U01r = cf[w]*c2 - sf[w]*c0, U01i = cf[w]*c3 - sf[w]*c1;
            const float U10r = cf[w]*c4 + sf[w]*c6, U10i = cf[w]*c5 + sf[w]*c7;
            const float U11r = cf[w]*c6 - sf[w]*c4, U11i = cf[w]*c7 - sf[w]*c5;

            if (w <= 5) {                 // state bit k=7-w>=2 -> lane bit (5-w)
                const int kb = 5 - w;
                const int xm = 1 << kb;
                const bool hi = (L >> kb) & 1;
                const float u0r = hi ? U11r : U00r;
                const float u0i = hi ? U11i : U00i;
                const float u1r = hi ? U10r : U01r;
                const float u1i = hi ? U10i : U01i;
                #pragma unroll
                for (int r = 0; r < 4; ++r) {
                    const float ore = __shfl_xor(re[r], xm, 64);
                    const float oim = __shfl_xor(im[r], xm, 64);
                    const float nre = u0r*re[r] - u0i*im[r] + u1r*ore - u1i*oim;
                    const float nim = u0r*im[r] + u0i*re[r] + u1r*oim + u1i*ore;
                    re[r] = nre; im[r] = nim;
                }
            } else if (w == 6) {          // state bit 1: pairs (r, r+2)
                float nre[4], nim[4];
                #pragma unroll
                for (int p = 0; p < 2; ++p) {
                    nre[p]   = U00r*re[p]-U00i*im[p] + U01r*re[p+2]-U01i*im[p+2];
                    nim[p]   = U00r*im[p]+U00i*re[p] + U01r*im[p+2]+U01i*re[p+2];
                    nre[p+2] = U10r*re[p]-U10i*im[p] + U11r*re[p+2]-U11i*im[p+2];
                    nim[p+2] = U10r*im[p]+U10i*re[p] + U11r*im[p+2]+U11i*re[p+2];
                }
                #pragma unroll
                for (int r = 0; r < 4; ++r) { re[r] = nre[r]; im[r] = nim[r]; }
            } else {                      // w==7, state bit 0: pairs (r, r+1)
                float nre[4], nim[4];
                #pragma unroll
                for (int p = 0; p < 4; p += 2) {
                    nre[p]   = U00r*re[p]-U00i*im[p] + U01r*re[p+1]-U01i*im[p+1];
                    nim[p]   = U00r*im[p]+U00i*re[p] + U01r*im[p+1]+U01i*re[p+1];
                    nre[p+1] = U10r*re[p]-U10i*im[p] + U11r*re[p+1]-U11i*im[p+1];
                    nim[p+1] = U10r*im[p]+U10i*re[p] + U11r*im[p+1]+U11i*re[p+1];
                }
                #pragma unroll
                for (int r = 0; r < 4; ++r) { re[r] = nre[r]; im[r] = nim[r]; }
            }
        }

        // -------- CNOT ring c -> (c+1)%8 ; ctrl bit 7-c, tgt bit 7-(c+1)
        // c=0..4: ctrl lane bit (5-c), tgt lane bit (4-c) -> shfl_xor(1<<(4-c))
        #pragma unroll
        for (int c = 0; c < 5; ++c) {
            const bool ctrl = (L >> (5 - c)) & 1;
            const int xm = 1 << (4 - c);
            #pragma unroll
            for (int r = 0; r < 4; ++r) {
                const float ore = __shfl_xor(re[r], xm, 64);
                const float oim = __shfl_xor(im[r], xm, 64);
                re[r] = ctrl ? ore : re[r];
                im[r] = ctrl ? oim : im[r];
            }
        }
        {   // c=5: ctrl lane bit 0, tgt register bit 1 (r -> r^2)
            const bool ctrl = L & 1;
            float nre[4], nim[4];
            #pragma unroll
            for (int r = 0; r < 4; ++r) {
                nre[r] = ctrl ? re[r ^ 2] : re[r];
                nim[r] = ctrl ? im[r ^ 2] : im[r];
            }
            #pragma unroll
            for (int r = 0; r < 4; ++r) { re[r] = nre[r]; im[r] = nim[r]; }
        }
        {   // c=6: ctrl register bit 1, tgt register bit 0: swap r2<->r3
            float tr = re[2]; re[2] = re[3]; re[3] = tr;
            float ti = im[2]; im[2] = im[3]; im[3] = ti;
        }
        {   // c=7: ctrl register bit 0, tgt state bit 7 (lane bit 5)
            #pragma unroll
            for (int r = 1; r < 4; r += 2) {
                re[r] = __shfl_xor(re[r], 32, 64);
                im[r] = __shfl_xor(im[r], 32, 64);
            }
        }
    }

    // ---- <Z_w> : sign = 1-2*bit_{7-w}(s)
    const float p0 = re[0]*re[0] + im[0]*im[0];
    const float p1 = re[1]*re[1] + im[1]*im[1];
    const float p2 = re[2]*re[2] + im[2]*im[2];
    const float p3 = re[3]*re[3] + im[3]*im[3];
    const float pt = p0 + p1 + p2 + p3;
    float z[8];
    #pragma unroll
    for (int w = 0; w < 6; ++w) z[w] = ((L >> (5 - w)) & 1) ? -pt : pt;
    z[6] = p0 + p1 - p2 - p3;
    z[7] = p0 - p1 + p2 - p3;
    #pragma unroll
    for (int w = 0; w < 8; ++w) {
        #pragma unroll
        for (int off = 1; off < 64; off <<= 1) z[w] += __shfl_xor(z[w], off, 64);
    }

    // ---- e = gelu(z @ W3 + b3) : lane writes cols 4L..4L+3
    const float4 b3v = *(const float4*)(b3 + 4 * L);
    float acc[4] = {b3v.x, b3v.y, b3v.z, b3v.w};
    #pragma unroll
    for (int w = 0; w < 8; ++w) {
        const float4 w3v = *(const float4*)(W3 + (size_t)w * 256 + 4 * L);
        acc[0] += z[w] * w3v.x; acc[1] += z[w] * w3v.y;
        acc[2] += z[w] * w3v.z; acc[3] += z[w] * w3v.w;
    }
    *(float4*)(e + (size_t)row * 256 + 4 * L) =
        make_float4(gelu_f(acc[0]), gelu_f(acc[1]), gelu_f(acc[2]), gelu_f(acc[3]));
}

// ---------------------------------------------------------------------------
// In-place LayerNorm over last dim (768). One block per row.
// ---------------------------------------------------------------------------
__global__ __launch_bounds__(256) void ln_kernel(
    float* __restrict__ y, const float* __restrict__ gamma,
    const float* __restrict__ beta)
{
    __shared__ float red[2][4];
    __shared__ float stats[2];
    const int row = blockIdx.x, t = threadIdx.x;
    const int lane = t & 63, wid = t >> 6;
    float* yr = y + (size_t)row * 768;
    const float v0 = yr[t], v1 = yr[t + 256], v2 = yr[t + 512];
    float s = v0 + v1 + v2;
    float q = v0 * v0 + v1 * v1 + v2 * v2;
    #pragma unroll
    for (int off = 32; off > 0; off >>= 1) {
        s += __shfl_down(s, off, 64);
        q += __shfl_down(q, off, 64);
    }
    if (lane == 0) { red[0][wid] = s; red[1][wid] = q; }
    __syncthreads();
    if (t == 0) {
        const float S = red[0][0] + red[0][1] + red[0][2] + red[0][3];
        const float Q = red[1][0] + red[1][1] + red[1][2] + red[1][3];
        const float mu = S * (1.0f / 768.0f);
        const float var = Q * (1.0f / 768.0f) - mu * mu;
        stats[0] = mu;
        stats[1] = rsqrtf(var + 1e-5f);
    }
    __syncthreads();
    const float mu = stats[0], rstd = stats[1];
    yr[t]       = gamma[t]       * (v0 - mu) * rstd + beta[t];
    yr[t + 256] = gamma[t + 256] * (v1 - mu) * rstd + beta[t + 256];
    yr[t + 512] = gamma[t + 512] * (v2 - mu) * rstd + beta[t + 512];
}

extern "C" void kernel_launch(void* const* d_in, const int* in_sizes, int n_in,
                              void* d_out, int out_size, void* d_ws, size_t ws_size,
                              hipStream_t stream) {
    (void)n_in; (void)out_size; (void)ws_size;
    const float* x     = (const float*)d_in[0];
    const float* W1    = (const float*)d_in[1];
    const float* b1    = (const float*)d_in[2];
    const float* W2    = (const float*)d_in[3];
    const float* b2    = (const float*)d_in[4];
    const float* qw    = (const float*)d_in[5];
    const float* W3    = (const float*)d_in[6];
    const float* b3    = (const float*)d_in[7];
    const float* W4    = (const float*)d_in[8];
    const float* b4    = (const float*)d_in[9];
    const float* gamma = (const float*)d_in[10];
    const float* beta  = (const float*)d_in[11];
    float* out = (float*)d_out;

    const int D = 768, H = 256;
    const int B = in_sizes[0] / D;     // 16384
    float* h = (float*)d_ws;           // B x 256
    float* e = h + (size_t)B * H;      // B x 256

    dim3 blk(256);
    gemm_kernel<0><<<dim3(H / 128, B / 64), blk, 0, stream>>>(x, W1, b1, nullptr, h, B, H, D);
    quantum_kernel<<<dim3(B / 4), blk, 0, stream>>>(h, W2, b2, qw, W3, b3, e);
    gemm_kernel<1><<<dim3(D / 128, B / 64), blk, 0, stream>>>(e, W4, b4, x, out, B, D, H);
    ln_kernel<<<dim3(B), blk, 0, stream>>>(out, gamma, beta);
}

// Round 3
// 277.396 us; speedup vs baseline: 1.5169x; 1.3173x over previous
//
#include <hip/hip_runtime.h>
#include <hip/hip_bf16.h>
#include <math.h>

// Pipeline: y = LN(x + gelu(Q(gelu(x@W1+b1)@W2+b2)@W3+b3)@W4+b4)
// Round 3: bf16-MFMA GEMMs.
//  - prep: W1,W4 transposed to bf16 [n][k] in ws (L2-resident afterwards)
//  - gemm1: BM=32 x BN=256(full), BK=32, mfma 16x16x32_bf16, A via LDS (pad
//    stride 40 bf16 -> <=2-way banks = free), B frags direct from W1bt.
//  - gemm4_ln: BM=16 x BN=768(full row), K=256 staged once to LDS -> k-loop
//    has no barriers; epilogue fuses bias + fp32 residual + LayerNorm.
// Quantum kernel unchanged (wave-local shfl sim).
// MFMA layouts (verified, guide §3): A/B frag [m|n=lane&15][k=(lane>>4)*8+j],
// C/D col=lane&15, row=(lane>>4)*4+reg.

typedef __attribute__((ext_vector_type(8))) short bf16x8;
typedef __attribute__((ext_vector_type(4))) float f32x4;

__device__ __forceinline__ float gelu_f(float x) {
    return 0.5f * x * (1.0f + erff(x * 0.70710678118654752f));
}

__device__ __forceinline__ short f2b(float x) {
    __hip_bfloat16 h = __float2bfloat16(x);
    return reinterpret_cast<short&>(h);
}

// ---------------------------------------------------------------------------
// 32x32 tiled transpose fp32[K][N] -> bf16[N][K]
// ---------------------------------------------------------------------------
__global__ __launch_bounds__(256) void transpose_bf16_kernel(
    const float* __restrict__ in, short* __restrict__ out, int K, int N)
{
    __shared__ float tl[32][33];
    const int k0 = blockIdx.y * 32, n0 = blockIdx.x * 32;
    const int r = threadIdx.x >> 3, c4 = (threadIdx.x & 7) * 4;
    const float4 v = *(const float4*)(in + (size_t)(k0 + r) * N + n0 + c4);
    tl[r][c4] = v.x; tl[r][c4 + 1] = v.y; tl[r][c4 + 2] = v.z; tl[r][c4 + 3] = v.w;
    __syncthreads();
    short4 o = make_short4(f2b(tl[c4][r]), f2b(tl[c4 + 1][r]),
                           f2b(tl[c4 + 2][r]), f2b(tl[c4 + 3][r]));
    *(short4*)(out + (size_t)(n0 + r) * K + k0 + c4) = o;
}

// ---------------------------------------------------------------------------
// GEMM1: h[M,256] = gelu(x[M,768] @ W1 + b1), W1bt = bf16 W1^T [256][768].
// BM=32, BN=256 (full), BK=32. 256 thr = 4 waves; wave w owns n-range 64w.
// Grid: M/32 blocks.
// ---------------------------------------------------------------------------
__global__ __launch_bounds__(256) void gemm1_kernel(
    const float* __restrict__ x, const short* __restrict__ W1bt,
    const float* __restrict__ b1, float* __restrict__ h, int M)
{
    __shared__ short As[32][40];   // [m][k], stride 40 bf16 (80 B): <=2-way banks

    const int tid = threadIdx.x;
    const int wv = tid >> 6, L = tid & 63;
    const int quad = L >> 4, r16 = L & 15;
    const int m0 = blockIdx.x * 32;
    const int n0 = wv * 64;

    // staging: thread -> 4 consecutive k at row m_s
    const int m_s = tid >> 3, k_s = (tid & 7) * 4;
    const float* xp = x + (size_t)(m0 + m_s) * 768 + k_s;

    // B fragment base: W1bt[n0 + nt*16 + r16][kt*32 + quad*8]
    const short* bp = W1bt + (size_t)(n0 + r16) * 768 + quad * 8;

    f32x4 acc[2][4];
    #pragma unroll
    for (int i = 0; i < 2; ++i)
        #pragma unroll
        for (int j = 0; j < 4; ++j) acc[i][j] = (f32x4){0.f, 0.f, 0.f, 0.f};

    for (int kt = 0; kt < 24; ++kt) {
        const float4 av = *(const float4*)(xp + kt * 32);
        __syncthreads();   // previous iter's ds_reads done
        *(short4*)&As[m_s][k_s] = make_short4(f2b(av.x), f2b(av.y), f2b(av.z), f2b(av.w));
        __syncthreads();
        const bf16x8 a0 = *(const bf16x8*)&As[r16][quad * 8];
        const bf16x8 a1 = *(const bf16x8*)&As[16 + r16][quad * 8];
        #pragma unroll
        for (int nt = 0; nt < 4; ++nt) {
            const bf16x8 bfr = *(const bf16x8*)(bp + (size_t)nt * 16 * 768 + kt * 32);
            acc[0][nt] = __builtin_amdgcn_mfma_f32_16x16x32_bf16(a0, bfr, acc[0][nt], 0, 0, 0);
            acc[1][nt] = __builtin_amdgcn_mfma_f32_16x16x32_bf16(a1, bfr, acc[1][nt], 0, 0, 0);
        }
    }

    // epilogue: C col = n0+16nt+r16, row = m0+16mt+quad*4+reg
    #pragma unroll
    for (int nt = 0; nt < 4; ++nt) {
        const int n = n0 + nt * 16 + r16;
        const float bv = b1[n];
        #pragma unroll
        for (int mt = 0; mt < 2; ++mt) {
            #pragma unroll
            for (int reg = 0; reg < 4; ++reg) {
                const int row = m0 + mt * 16 + quad * 4 + reg;
                h[(size_t)row * 256 + n] = gelu_f(acc[mt][nt][reg] + bv);
            }
        }
    }
}

// ---------------------------------------------------------------------------
// GEMM4+LN: y = e[M,256] @ W4 + b4 + x ; out = LN(y)*gamma + beta
// W4bt = bf16 W4^T [768][256]. BM=16, BN=768 (full row), K=256 (fully staged).
// 256 thr = 4 waves; wave w owns n-range 192w (12 n-tiles). Grid: M/16.
// ---------------------------------------------------------------------------
__global__ __launch_bounds__(256) void gemm4_ln_kernel(
    const float* __restrict__ e, const short* __restrict__ W4bt,
    const float* __restrict__ b4, const float* __restrict__ x,
    const float* __restrict__ gamma, const float* __restrict__ beta,
    float* __restrict__ out, int M)
{
    __shared__ short Ae[16][264];      // [m][k], stride 264 bf16: <=2-way banks
    __shared__ float red[4][16][2];
    __shared__ float stats[16][2];

    const int tid = threadIdx.x;
    const int wv = tid >> 6, L = tid & 63;
    const int quad = L >> 4, r16 = L & 15;
    const int m0 = blockIdx.x * 16;
    const int n0 = wv * 192;

    // stage A (e rows m0..m0+15, all K=256) as bf16
    {
        const int m_s = tid >> 4, k_s = (tid & 15) * 16;
        const float* ep = e + (size_t)(m0 + m_s) * 256 + k_s;
        #pragma unroll
        for (int i = 0; i < 4; ++i) {
            const float4 v = *(const float4*)(ep + 4 * i);
            *(short4*)&Ae[m_s][k_s + 4 * i] =
                make_short4(f2b(v.x), f2b(v.y), f2b(v.z), f2b(v.w));
        }
    }
    __syncthreads();

    const short* bp = W4bt + (size_t)(n0 + r16) * 256 + quad * 8;

    f32x4 acc[12];
    #pragma unroll
    for (int nt = 0; nt < 12; ++nt) acc[nt] = (f32x4){0.f, 0.f, 0.f, 0.f};

    for (int kt = 0; kt < 8; ++kt) {
        const bf16x8 af = *(const bf16x8*)&Ae[r16][kt * 32 + quad * 8];
        #pragma unroll
        for (int nt = 0; nt < 12; ++nt) {
            const bf16x8 bfr = *(const bf16x8*)(bp + (size_t)nt * 16 * 256 + kt * 32);
            acc[nt] = __builtin_amdgcn_mfma_f32_16x16x32_bf16(af, bfr, acc[nt], 0, 0, 0);
        }
    }

    // y = acc + b4 + x ; accumulate LN partials
    float ps[4] = {0.f, 0.f, 0.f, 0.f}, pq[4] = {0.f, 0.f, 0.f, 0.f};
    #pragma unroll
    for (int nt = 0; nt < 12; ++nt) {
        const int n = n0 + nt * 16 + r16;
        const float bv = b4[n];
        #pragma unroll
        for (int reg = 0; reg < 4; ++reg) {
            const int row = m0 + quad * 4 + reg;
            const float y = acc[nt][reg] + bv + x[(size_t)row * 768 + n];
            acc[nt][reg] = y;
            ps[reg] += y;
            pq[reg] += y * y;
        }
    }
    #pragma unroll
    for (int off = 1; off < 16; off <<= 1) {
        #pragma unroll
        for (int reg = 0; reg < 4; ++reg) {
            ps[reg] += __shfl_xor(ps[reg], off, 64);
            pq[reg] += __shfl_xor(pq[reg], off, 64);
        }
    }
    if (r16 == 0) {
        #pragma unroll
        for (int reg = 0; reg < 4; ++reg) {
            red[wv][quad * 4 + reg][0] = ps[reg];
            red[wv][quad * 4 + reg][1] = pq[reg];
        }
    }
    __syncthreads();
    if (tid < 16) {
        const float S = red[0][tid][0] + red[1][tid][0] + red[2][tid][0] + red[3][tid][0];
        const float Q = red[0][tid][1] + red[1][tid][1] + red[2][tid][1] + red[3][tid][1];
        const float mu = S * (1.0f / 768.0f);
        const float var = Q * (1.0f / 768.0f) - mu * mu;
        stats[tid][0] = mu;
        stats[tid][1] = rsqrtf(var + 1e-5f);
    }
    __syncthreads();

    float mu_r[4], rs_r[4];
    #pragma unroll
    for (int reg = 0; reg < 4; ++reg) {
        mu_r[reg] = stats[quad * 4 + reg][0];
        rs_r[reg] = stats[quad * 4 + reg][1];
    }
    #pragma unroll
    for (int nt = 0; nt < 12; ++nt) {
        const int n = n0 + nt * 16 + r16;
        const float g = gamma[n], bt = beta[n];
        #pragma unroll
        for (int reg = 0; reg < 4; ++reg) {
            const int row = m0 + quad * 4 + reg;
            out[(size_t)row * 768 + n] = g * (acc[nt][reg] - mu_r[reg]) * rs_r[reg] + bt;
        }
    }
}

// ---------------------------------------------------------------------------
// Wave-local fused: feats = h@W2+b2 ; z = quantum(feats) ; e = gelu(z@W3+b3)
// (unchanged from round 2)
// ---------------------------------------------------------------------------
__global__ __launch_bounds__(256) void quantum_kernel(
    const float* __restrict__ h, const float* __restrict__ W2,
    const float* __restrict__ b2, const float* __restrict__ qw,
    const float* __restrict__ W3, const float* __restrict__ b3,
    float* __restrict__ e)
{
    const int t = threadIdx.x;
    const int wid = t >> 6, L = t & 63;
    const int row = blockIdx.x * 4 + wid;

    const float4 hv = *(const float4*)(h + (size_t)row * 256 + L * 4);
    const float hr[4] = {hv.x, hv.y, hv.z, hv.w};
    float f[8];
    #pragma unroll
    for (int w = 0; w < 8; ++w) f[w] = 0.0f;
    #pragma unroll
    for (int r = 0; r < 4; ++r) {
        const float4 wa = *(const float4*)(W2 + (size_t)(4 * L + r) * 8);
        const float4 wb = *(const float4*)(W2 + (size_t)(4 * L + r) * 8 + 4);
        f[0] += hr[r] * wa.x; f[1] += hr[r] * wa.y;
        f[2] += hr[r] * wa.z; f[3] += hr[r] * wa.w;
        f[4] += hr[r] * wb.x; f[5] += hr[r] * wb.y;
        f[6] += hr[r] * wb.z; f[7] += hr[r] * wb.w;
    }
    #pragma unroll
    for (int w = 0; w < 8; ++w) {
        #pragma unroll
        for (int off = 1; off < 64; off <<= 1) f[w] += __shfl_xor(f[w], off, 64);
        f[w] += b2[w];
    }

    float cf[8], sf[8];
    #pragma unroll
    for (int w = 0; w < 8; ++w) sincosf(0.5f * f[w], &sf[w], &cf[w]);

    float cc[8];
    {
        const int g = L & 15;
        const float w0 = qw[g * 3 + 0];
        const float w1 = qw[g * 3 + 1];
        const float w2 = qw[g * 3 + 2];
        const float a0 = 0.5f * w0, a2 = 0.5f * w2;
        float s1, c1; sincosf(0.5f * w1, &s1, &c1);
        float sp, cp; sincosf(a0 + a2, &sp, &cp);
        float sm, cm; sincosf(a0 - a2, &sm, &cm);
        cc[0] =  c1 * cp;  cc[1] = -c1 * sp;
        cc[2] = -s1 * cm;  cc[3] = -s1 * sm;
        cc[4] =  s1 * cm;  cc[5] = -s1 * sm;
        cc[6] =  c1 * cp;  cc[7] =  c1 * sp;
    }

    float re[4], im[4];
    #pragma unroll
    for (int r = 0; r < 4; ++r) { re[r] = 0.0f; im[r] = 0.0f; }
    re[0] = (L == 0) ? 1.0f : 0.0f;

    #pragma unroll
    for (int l = 0; l < 2; ++l) {
        #pragma unroll
        for (int w = 0; w < 8; ++w) {
            const int g = l * 8 + w;
            const float c0 = __shfl(cc[0], g, 64), c1 = __shfl(cc[1], g, 64);
            const float c2 = __shfl(cc[2], g, 64), c3 = __shfl(cc[3], g, 64);
            const float c4 = __shfl(cc[4], g, 64), c5 = __shfl(cc[5], g, 64);
            const float c6 = __shfl(cc[6], g, 64), c7 = __shfl(cc[7], g, 64);
            const float U00r = cf[w]*c0 + sf[w]*c2, U00i = cf[w]*c1 + sf[w]*c3;
            const float U01r = cf[w]*c2 - sf[w]*c0, U01i = cf[w]*c3 - sf[w]*c1;
            const float U10r = cf[w]*c4 + sf[w]*c6, U10i = cf[w]*c5 + sf[w]*c7;
            const float U11r = cf[w]*c6 - sf[w]*c4, U11i = cf[w]*c7 - sf[w]*c5;

            if (w <= 5) {
                const int kb = 5 - w;
                const int xm = 1 << kb;
                const bool hi = (L >> kb) & 1;
                const float u0r = hi ? U11r : U00r;
                const float u0i = hi ? U11i : U00i;
                const float u1r = hi ? U10r : U01r;
                const float u1i = hi ? U10i : U01i;
                #pragma unroll
                for (int r = 0; r < 4; ++r) {
                    const float ore = __shfl_xor(re[r], xm, 64);
                    const float oim = __shfl_xor(im[r], xm, 64);
                    const float nre = u0r*re[r] - u0i*im[r] + u1r*ore - u1i*oim;
                    const float nim = u0r*im[r] + u0i*re[r] + u1r*oim + u1i*ore;
                    re[r] = nre; im[r] = nim;
                }
            } else if (w == 6) {
                float nre[4], nim[4];
                #pragma unroll
                for (int p = 0; p < 2; ++p) {
                    nre[p]   = U00r*re[p]-U00i*im[p] + U01r*re[p+2]-U01i*im[p+2];
                    nim[p]   = U00r*im[p]+U00i*re[p] + U01r*im[p+2]+U01i*re[p+2];
                    nre[p+2] = U10r*re[p]-U10i*im[p] + U11r*re[p+2]-U11i*im[p+2];
                    nim[p+2] = U10r*im[p]+U10i*re[p] + U11r*im[p+2]+U11i*re[p+2];
                }
                #pragma unroll
                for (int r = 0; r < 4; ++r) { re[r] = nre[r]; im[r] = nim[r]; }
            } else {
                float nre[4], nim[4];
                #pragma unroll
                for (int p = 0; p < 4; p += 2) {
                    nre[p]   = U00r*re[p]-U00i*im[p] + U01r*re[p+1]-U01i*im[p+1];
                    nim[p]   = U00r*im[p]+U00i*re[p] + U01r*im[p+1]+U01i*re[p+1];
                    nre[p+1] = U10r*re[p]-U10i*im[p] + U11r*re[p+1]-U11i*im[p+1];
                    nim[p+1] = U10r*im[p]+U10i*re[p] + U11r*im[p+1]+U11i*re[p+1];
                }
                #pragma unroll
                for (int r = 0; r < 4; ++r) { re[r] = nre[r]; im[r] = nim[r]; }
            }
        }

        #pragma unroll
        for (int c = 0; c < 5; ++c) {
            const bool ctrl = (L >> (5 - c)) & 1;
            const int xm = 1 << (4 - c);
            #pragma unroll
            for (int r = 0; r < 4; ++r) {
                const float ore = __shfl_xor(re[r], xm, 64);
                const float oim = __shfl_xor(im[r], xm, 64);
                re[r] = ctrl ? ore : re[r];
                im[r] = ctrl ? oim : im[r];
            }
        }
        {
            const bool ctrl = L & 1;
            float nre[4], nim[4];
            #pragma unroll
            for (int r = 0; r < 4; ++r) {
                nre[r] = ctrl ? re[r ^ 2] : re[r];
                nim[r] = ctrl ? im[r ^ 2] : im[r];
            }
            #pragma unroll
            for (int r = 0; r < 4; ++r) { re[r] = nre[r]; im[r] = nim[r]; }
        }
        {
            float tr = re[2]; re[2] = re[3]; re[3] = tr;
            float ti = im[2]; im[2] = im[3]; im[3] = ti;
        }
        {
            #pragma unroll
            for (int r = 1; r < 4; r += 2) {
                re[r] = __shfl_xor(re[r], 32, 64);
                im[r] = __shfl_xor(im[r], 32, 64);
            }
        }
    }

    const float p0 = re[0]*re[0] + im[0]*im[0];
    const float p1 = re[1]*re[1] + im[1]*im[1];
    const float p2 = re[2]*re[2] + im[2]*im[2];
    const float p3 = re[3]*re[3] + im[3]*im[3];
    const float pt = p0 + p1 + p2 + p3;
    float z[8];
    #pragma unroll
    for (int w = 0; w < 6; ++w) z[w] = ((L >> (5 - w)) & 1) ? -pt : pt;
    z[6] = p0 + p1 - p2 - p3;
    z[7] = p0 - p1 + p2 - p3;
    #pragma unroll
    for (int w = 0; w < 8; ++w) {
        #pragma unroll
        for (int off = 1; off < 64; off <<= 1) z[w] += __shfl_xor(z[w], off, 64);
    }

    const float4 b3v = *(const float4*)(b3 + 4 * L);
    float acc[4] = {b3v.x, b3v.y, b3v.z, b3v.w};
    #pragma unroll
    for (int w = 0; w < 8; ++w) {
        const float4 w3v = *(const float4*)(W3 + (size_t)w * 256 + 4 * L);
        acc[0] += z[w] * w3v.x; acc[1] += z[w] * w3v.y;
        acc[2] += z[w] * w3v.z; acc[3] += z[w] * w3v.w;
    }
    *(float4*)(e + (size_t)row * 256 + 4 * L) =
        make_float4(gelu_f(acc[0]), gelu_f(acc[1]), gelu_f(acc[2]), gelu_f(acc[3]));
}

extern "C" void kernel_launch(void* const* d_in, const int* in_sizes, int n_in,
                              void* d_out, int out_size, void* d_ws, size_t ws_size,
                              hipStream_t stream) {
    (void)n_in; (void)out_size; (void)ws_size;
    const float* x     = (const float*)d_in[0];
    const float* W1    = (const float*)d_in[1];
    const float* b1    = (const float*)d_in[2];
    const float* W2    = (const float*)d_in[3];
    const float* b2    = (const float*)d_in[4];
    const float* qw    = (const float*)d_in[5];
    const float* W3    = (const float*)d_in[6];
    const float* b3    = (const float*)d_in[7];
    const float* W4    = (const float*)d_in[8];
    const float* b4    = (const float*)d_in[9];
    const float* gamma = (const float*)d_in[10];
    const float* beta  = (const float*)d_in[11];
    float* out = (float*)d_out;

    const int D = 768, H = 256;
    const int B = in_sizes[0] / D;                 // 16384

    short* W1bt = (short*)d_ws;                    // 256 x 768 bf16
    short* W4bt = W1bt + (size_t)H * D;            // 768 x 256 bf16
    float* h    = (float*)(W4bt + (size_t)D * H);  // B x 256 f32
    float* e    = h + (size_t)B * H;               // B x 256 f32

    transpose_bf16_kernel<<<dim3(H / 32, D / 32), 256, 0, stream>>>(W1, W1bt, D, H);
    transpose_bf16_kernel<<<dim3(D / 32, H / 32), 256, 0, stream>>>(W4, W4bt, H, D);
    gemm1_kernel<<<dim3(B / 32), 256, 0, stream>>>(x, W1bt, b1, h, B);
    quantum_kernel<<<dim3(B / 4), 256, 0, stream>>>(h, W2, b2, qw, W3, b3, e);
    gemm4_ln_kernel<<<dim3(B / 16), 256, 0, stream>>>(e, W4bt, b4, x, gamma, beta, out, B);
}

// Round 4
// 234.094 us; speedup vs baseline: 1.7975x; 1.1850x over previous
//
#include <hip/hip_runtime.h>
#include <hip/hip_bf16.h>
#include <math.h>

// Pipeline: y = LN(x + gelu(Q(gelu(x@W1+b1)@W2+b2)@W3+b3)@W4+b4)
// Round 4:
//  - h never materialized: gemm1 fuses feats = gelu(x@W1+b1)@W2+b2 (LDS
//    round-trip + MFMA vs zero-padded W2^T).  -32 MB HBM.
//  - quantum v3: gate matrices C precomputed once (setup_kernel, row-indep);
//    CNOT ring composed into ONE linear permutation (Gray-code lane map,
//    8 shfl + 8 sel per ring); <Z> via merge-tree reduction. ~150 DS ops/wave
//    (was ~408). e written as bf16.
//  - gemm1: BM=64xBN=256, 512thr, double-buffered LDS, 2-deep reg prefetch,
//    1 barrier per k-tile. gemm4_ln: bf16 e input, fused LayerNorm.

typedef __attribute__((ext_vector_type(8))) short bf16x8;
typedef __attribute__((ext_vector_type(4))) float f32x4;

__device__ __forceinline__ float gelu_f(float x) {
    return 0.5f * x * (1.0f + erff(x * 0.70710678118654752f));
}

__device__ __forceinline__ short f2b(float x) {
    __hip_bfloat16 h = __float2bfloat16(x);
    return reinterpret_cast<short&>(h);
}

__device__ __forceinline__ short4 f4_to_b4(float4 v) {
    return make_short4(f2b(v.x), f2b(v.y), f2b(v.z), f2b(v.w));
}

// ---------------------------------------------------------------------------
// 32x32 tiled transpose fp32[K][N] -> bf16[N][K]
// ---------------------------------------------------------------------------
__global__ __launch_bounds__(256) void transpose_bf16_kernel(
    const float* __restrict__ in, short* __restrict__ out, int K, int N)
{
    __shared__ float tl[32][33];
    const int k0 = blockIdx.y * 32, n0 = blockIdx.x * 32;
    const int r = threadIdx.x >> 3, c4 = (threadIdx.x & 7) * 4;
    const float4 v = *(const float4*)(in + (size_t)(k0 + r) * N + n0 + c4);
    tl[r][c4] = v.x; tl[r][c4 + 1] = v.y; tl[r][c4 + 2] = v.z; tl[r][c4 + 3] = v.w;
    __syncthreads();
    short4 o = make_short4(f2b(tl[c4][r]), f2b(tl[c4 + 1][r]),
                           f2b(tl[c4 + 2][r]), f2b(tl[c4 + 3][r]));
    *(short4*)(out + (size_t)(n0 + r) * K + k0 + c4) = o;
}

// ---------------------------------------------------------------------------
// setup: Cg[16][8] = RZ(w2)RY(w1)RZ(w0) per (layer,wire); W2T[16][256] bf16
// (row n<8 = W2[:,n], rows 8..15 zero)
// ---------------------------------------------------------------------------
__global__ __launch_bounds__(256) void setup_kernel(
    const float* __restrict__ qw, const float* __restrict__ W2,
    float* __restrict__ Cg, short* __restrict__ W2T)
{
    const int t = threadIdx.x;
    if (t < 16) {
        const float w0 = qw[t * 3 + 0];
        const float w1 = qw[t * 3 + 1];
        const float w2 = qw[t * 3 + 2];
        const float a0 = 0.5f * w0, a2 = 0.5f * w2;
        float s1, c1; sincosf(0.5f * w1, &s1, &c1);
        float sp, cp; sincosf(a0 + a2, &sp, &cp);   // e^{-i(a0+a2)} = cp - i sp
        float sm, cm; sincosf(a0 - a2, &sm, &cm);   // e^{+i(a0-a2)} = cm + i sm
        Cg[t * 8 + 0] =  c1 * cp;  Cg[t * 8 + 1] = -c1 * sp;   // C00
        Cg[t * 8 + 2] = -s1 * cm;  Cg[t * 8 + 3] = -s1 * sm;   // C01
        Cg[t * 8 + 4] =  s1 * cm;  Cg[t * 8 + 5] = -s1 * sm;   // C10
        Cg[t * 8 + 6] =  c1 * cp;  Cg[t * 8 + 7] =  c1 * sp;   // C11
    }
    for (int idx = t; idx < 16 * 256; idx += 256) {
        const int n = idx & 15, k = idx >> 4;
        W2T[(size_t)n * 256 + k] = (n < 8) ? f2b(W2[(size_t)k * 8 + n]) : (short)0;
    }
}

// ---------------------------------------------------------------------------
// GEMM1+feats: feats[M,8] = gelu(x[M,768]@W1+b1)@W2 + b2
// BM=64, BN=256(full), BK=32, 512 thr = 8 waves (mw in 0..1, nw in 0..3).
// Double-buffered A staging, 2-deep register prefetch, 1 barrier/kt.
// Epilogue: h-block (gelu'd, bf16) -> LDS -> 8 MFMAs vs W2T -> feats.
// Grid: M/64.
// ---------------------------------------------------------------------------
__global__ __launch_bounds__(512) void gemm1_feats_kernel(
    const float* __restrict__ x, const short* __restrict__ W1bt,
    const float* __restrict__ b1, const short* __restrict__ W2T,
    const float* __restrict__ b2, float* __restrict__ feats, int M)
{
    __shared__ short As[2][64][40];    // [buf][m][k], stride 40: <=2-way banks
    __shared__ short hb[64][264];      // gelu(h) block, [m][n], pad 264

    const int tid = threadIdx.x;
    const int wid = tid >> 6, L = tid & 63;
    const int quad = L >> 4, r16 = L & 15;
    const int mw = wid & 1, nw = wid >> 1;
    const int m0 = blockIdx.x * 64;

    const int m_s = tid >> 3, k_s = (tid & 7) << 2;
    const float* xp = x + (size_t)(m0 + m_s) * 768 + k_s;

    const short* bp = W1bt + (size_t)(nw * 64 + r16) * 768 + quad * 8;

    f32x4 acc[2][4];
    #pragma unroll
    for (int i = 0; i < 2; ++i)
        #pragma unroll
        for (int j = 0; j < 4; ++j) acc[i][j] = (f32x4){0.f, 0.f, 0.f, 0.f};

    // prologue: kt=0 into buf0; kt=1 held in regs
    float4 v0 = *(const float4*)(xp);
    *(short4*)&As[0][m_s][k_s] = f4_to_b4(v0);
    float4 v1 = *(const float4*)(xp + 32);
    __syncthreads();

    for (int kt = 0; kt < 24; ++kt) {
        const int buf = kt & 1;
        float4 vn = v1;
        if (kt + 2 < 24) vn = *(const float4*)(xp + (kt + 2) * 32);

        const bf16x8 a0 = *(const bf16x8*)&As[buf][32 * mw + r16][quad * 8];
        const bf16x8 a1 = *(const bf16x8*)&As[buf][32 * mw + 16 + r16][quad * 8];
        #pragma unroll
        for (int nt = 0; nt < 4; ++nt) {
            const bf16x8 bfr = *(const bf16x8*)(bp + (size_t)nt * 16 * 768 + kt * 32);
            acc[0][nt] = __builtin_amdgcn_mfma_f32_16x16x32_bf16(a0, bfr, acc[0][nt], 0, 0, 0);
            acc[1][nt] = __builtin_amdgcn_mfma_f32_16x16x32_bf16(a1, bfr, acc[1][nt], 0, 0, 0);
        }
        if (kt + 1 < 24) {
            *(short4*)&As[buf ^ 1][m_s][k_s] = f4_to_b4(v1);   // data for kt+1
        }
        __syncthreads();
        v1 = vn;
    }

    // epilogue: gelu + bias -> hb (bf16)
    #pragma unroll
    for (int mt = 0; mt < 2; ++mt) {
        #pragma unroll
        for (int nt = 0; nt < 4; ++nt) {
            const int n = nw * 64 + nt * 16 + r16;
            const float bv = b1[n];
            #pragma unroll
            for (int reg = 0; reg < 4; ++reg) {
                const int rrow = 32 * mw + 16 * mt + quad * 4 + reg;
                hb[rrow][n] = f2b(gelu_f(acc[mt][nt][reg] + bv));
            }
        }
    }
    __syncthreads();

    // feats = hb @ W2T^T + b2 : waves 0..3, wave = m-tile
    if (wid < 4) {
        const int mt = wid;
        f32x4 fa = (f32x4){0.f, 0.f, 0.f, 0.f};
        #pragma unroll
        for (int kt = 0; kt < 8; ++kt) {
            const bf16x8 ha = *(const bf16x8*)&hb[16 * mt + r16][kt * 32 + quad * 8];
            const bf16x8 wb = *(const bf16x8*)(W2T + (size_t)r16 * 256 + kt * 32 + quad * 8);
            fa = __builtin_amdgcn_mfma_f32_16x16x32_bf16(ha, wb, fa, 0, 0, 0);
        }
        if (r16 < 8) {
            const float bv = b2[r16];
            #pragma unroll
            for (int reg = 0; reg < 4; ++reg) {
                const int row = m0 + 16 * mt + quad * 4 + reg;
                feats[(size_t)row * 8 + r16] = fa[reg] + bv;
            }
        }
    }
}

// ---------------------------------------------------------------------------
// Quantum v3: one wave per row. State s=(L<<2)|r. Wire w -> state bit 7-w.
// Gates from precomputed Cg (uniform s_loads). CNOT ring = one composed
// permutation: src wire-bits b0=b0'^b7', b1=b1'^b0'^b7', bk=bk'^b(k-1)'.
// In lane coords: src_lane = (L^(L>>1)) ^ (48 if dest reg odd); src reg
// selected on SOURCE lane by parity(L). e written bf16.
// ---------------------------------------------------------------------------
__global__ __launch_bounds__(256) void quantum_kernel(
    const float* __restrict__ feats, const float* __restrict__ Cg,
    const float* __restrict__ W3, const float* __restrict__ b3,
    short* __restrict__ ebt)
{
    const int t = threadIdx.x;
    const int wid = t >> 6, L = t & 63;
    const int row = blockIdx.x * 4 + wid;

    // RY(feat) terms: lane w holds angle w; 1 sincos + 16 broadcasts
    const float fv = feats[(size_t)row * 8 + (L & 7)];
    float sv, cv;
    sincosf(0.5f * fv, &sv, &cv);
    float cf[8], sf[8];
    #pragma unroll
    for (int w = 0; w < 8; ++w) {
        cf[w] = __shfl(cv, w, 64);
        sf[w] = __shfl(sv, w, 64);
    }

    float re[4], im[4];
    #pragma unroll
    for (int r = 0; r < 4; ++r) { re[r] = 0.0f; im[r] = 0.0f; }
    re[0] = (L == 0) ? 1.0f : 0.0f;

    const int G = L ^ (L >> 1);        // Gray code of lane (bits 0..5)
    const int mapB = G ^ 48;
    const bool par = __popc(L) & 1;    // = dest-lane bit0 for both maps

    #pragma unroll
    for (int l = 0; l < 2; ++l) {
        #pragma unroll
        for (int w = 0; w < 8; ++w) {
            const float* Cw = Cg + (l * 8 + w) * 8;  // uniform -> s_load
            const float c0 = Cw[0], c1 = Cw[1], c2 = Cw[2], c3 = Cw[3];
            const float c4 = Cw[4], c5 = Cw[5], c6 = Cw[6], c7 = Cw[7];
            const float U00r = cf[w]*c0 + sf[w]*c2, U00i = cf[w]*c1 + sf[w]*c3;
            const float U01r = cf[w]*c2 - sf[w]*c0, U01i = cf[w]*c3 - sf[w]*c1;
            const float U10r = cf[w]*c4 + sf[w]*c6, U10i = cf[w]*c5 + sf[w]*c7;
            const float U11r = cf[w]*c6 - sf[w]*c4, U11i = cf[w]*c7 - sf[w]*c5;

            if (w <= 5) {                 // state bit 7-w -> lane bit 5-w
                const int kb = 5 - w;
                const int xm = 1 << kb;
                const bool hi = (L >> kb) & 1;
                const float u0r = hi ? U11r : U00r;
                const float u0i = hi ? U11i : U00i;
                const float u1r = hi ? U10r : U01r;
                const float u1i = hi ? U10i : U01i;
                #pragma unroll
                for (int r = 0; r < 4; ++r) {
                    const float ore = __shfl_xor(re[r], xm, 64);
                    const float oim = __shfl_xor(im[r], xm, 64);
                    const float nre = u0r*re[r] - u0i*im[r] + u1r*ore - u1i*oim;
                    const float nim = u0r*im[r] + u0i*re[r] + u1r*oim + u1i*ore;
                    re[r] = nre; im[r] = nim;
                }
            } else if (w == 6) {          // state bit 1: pairs (r, r+2)
                float nre[4], nim[4];
                #pragma unroll
                for (int p = 0; p < 2; ++p) {
                    nre[p]   = U00r*re[p]-U00i*im[p] + U01r*re[p+2]-U01i*im[p+2];
                    nim[p]   = U00r*im[p]+U00i*re[p] + U01r*im[p+2]+U01i*re[p+2];
                    nre[p+2] = U10r*re[p]-U10i*im[p] + U11r*re[p+2]-U11i*im[p+2];
                    nim[p+2] = U10r*im[p]+U10i*re[p] + U11r*im[p+2]+U11i*re[p+2];
                }
                #pragma unroll
                for (int r = 0; r < 4; ++r) { re[r] = nre[r]; im[r] = nim[r]; }
            } else {                      // w==7, state bit 0: pairs (r, r+1)
                float nre[4], nim[4];
                #pragma unroll
                for (int p = 0; p < 4; p += 2) {
                    nre[p]   = U00r*re[p]-U00i*im[p] + U01r*re[p+1]-U01i*im[p+1];
                    nim[p]   = U00r*im[p]+U00i*re[p] + U01r*im[p+1]+U01i*re[p+1];
                    nre[p+1] = U10r*re[p]-U10i*im[p] + U11r*re[p+1]-U11i*im[p+1];
                    nim[p+1] = U10r*im[p]+U10i*re[p] + U11r*im[p+1]+U11i*re[p+1];
                }
                #pragma unroll
                for (int r = 0; r < 4; ++r) { re[r] = nre[r]; im[r] = nim[r]; }
            }
        }

        // composed CNOT ring: new[L][r'] = old[srcreg(par(S))][S]
        {
            const float s0r = par ? re[2] : re[0], s0i = par ? im[2] : im[0];
            const float s1r = par ? re[3] : re[1], s1i = par ? im[3] : im[1];
            const float s2r = par ? re[1] : re[3], s2i = par ? im[1] : im[3];
            const float s3r = par ? re[0] : re[2], s3i = par ? im[0] : im[2];
            re[0] = __shfl(s0r, G, 64);    im[0] = __shfl(s0i, G, 64);
            re[1] = __shfl(s1r, mapB, 64); im[1] = __shfl(s1i, mapB, 64);
            re[2] = __shfl(s2r, G, 64);    im[2] = __shfl(s2i, G, 64);
            re[3] = __shfl(s3r, mapB, 64); im[3] = __shfl(s3i, mapB, 64);
        }
    }

    // <Z_w>: per-lane contributions, merge-tree + butterfly + broadcast
    const float p0 = re[0]*re[0] + im[0]*im[0];
    const float p1 = re[1]*re[1] + im[1]*im[1];
    const float p2 = re[2]*re[2] + im[2]*im[2];
    const float p3 = re[3]*re[3] + im[3]*im[3];
    const float pt = p0 + p1 + p2 + p3;
    float v[8];
    #pragma unroll
    for (int w = 0; w < 6; ++w) v[w] = ((L >> (5 - w)) & 1) ? -pt : pt;
    v[6] = p0 + p1 - p2 - p3;
    v[7] = p0 - p1 + p2 - p3;
    #pragma unroll
    for (int j = 0; j < 4; ++j) {     // offset 1: keep by L0 (w bit2)
        const float send = (L & 1) ? v[j] : v[j + 4];
        const float keep = (L & 1) ? v[j + 4] : v[j];
        v[j] = keep + __shfl_xor(send, 1, 64);
    }
    #pragma unroll
    for (int j = 0; j < 2; ++j) {     // offset 2: keep by L1 (w bit1)
        const float send = (L & 2) ? v[j] : v[j + 2];
        const float keep = (L & 2) ? v[j + 2] : v[j];
        v[j] = keep + __shfl_xor(send, 2, 64);
    }
    {                                  // offset 4: keep by L2 (w bit0)
        const float send = (L & 4) ? v[0] : v[1];
        const float keep = (L & 4) ? v[1] : v[0];
        v[0] = keep + __shfl_xor(send, 4, 64);
    }
    v[0] += __shfl_xor(v[0], 8, 64);
    v[0] += __shfl_xor(v[0], 16, 64);
    v[0] += __shfl_xor(v[0], 32, 64);
    // lane L holds z_{w}, w = 4*L0 + 2*L1 + L2 ; broadcast back
    float z[8];
    #pragma unroll
    for (int w = 0; w < 8; ++w) {
        const int src = ((w & 1) << 2) | (w & 2) | ((w >> 2) & 1);
        z[w] = __shfl(v[0], src, 64);
    }

    // e = gelu(z @ W3 + b3), store bf16: lane owns cols 4L..4L+3
    const float4 b3v = *(const float4*)(b3 + 4 * L);
    float acc[4] = {b3v.x, b3v.y, b3v.z, b3v.w};
    #pragma unroll
    for (int w = 0; w < 8; ++w) {
        const float4 w3v = *(const float4*)(W3 + (size_t)w * 256 + 4 * L);
        acc[0] += z[w] * w3v.x; acc[1] += z[w] * w3v.y;
        acc[2] += z[w] * w3v.z; acc[3] += z[w] * w3v.w;
    }
    *(short4*)(ebt + (size_t)row * 256 + 4 * L) =
        make_short4(f2b(gelu_f(acc[0])), f2b(gelu_f(acc[1])),
                    f2b(gelu_f(acc[2])), f2b(gelu_f(acc[3])));
}

// ---------------------------------------------------------------------------
// GEMM4+LN: y = e[M,256]@W4 + b4 + x ; out = LN(y)*gamma + beta
// e is bf16. BM=16, BN=768(full row), K=256 staged once -> barrier-free
// k-loop. Grid: M/16.
// ---------------------------------------------------------------------------
__global__ __launch_bounds__(256) void gemm4_ln_kernel(
    const short* __restrict__ ebt, const short* __restrict__ W4bt,
    const float* __restrict__ b4, const float* __restrict__ x,
    const float* __restrict__ gamma, const float* __restrict__ beta,
    float* __restrict__ out, int M)
{
    __shared__ short Ae[16][264];
    __shared__ float red[4][16][2];
    __shared__ float stats[16][2];

    const int tid = threadIdx.x;
    const int wv = tid >> 6, L = tid & 63;
    const int quad = L >> 4, r16 = L & 15;
    const int m0 = blockIdx.x * 16;
    const int n0 = wv * 192;

    {
        const int m_s = tid >> 4, k16 = (tid & 15) * 16;
        const int4* ep = (const int4*)(ebt + (size_t)(m0 + m_s) * 256 + k16);
        const int4 e0 = ep[0], e1 = ep[1];
        *(int4*)&Ae[m_s][k16] = e0;
        *(int4*)&Ae[m_s][k16 + 8] = e1;
    }
    __syncthreads();

    const short* bp = W4bt + (size_t)(n0 + r16) * 256 + quad * 8;

    f32x4 acc[12];
    #pragma unroll
    for (int nt = 0; nt < 12; ++nt) acc[nt] = (f32x4){0.f, 0.f, 0.f, 0.f};

    for (int kt = 0; kt < 8; ++kt) {
        const bf16x8 af = *(const bf16x8*)&Ae[r16][kt * 32 + quad * 8];
        #pragma unroll
        for (int nt = 0; nt < 12; ++nt) {
            const bf16x8 bfr = *(const bf16x8*)(bp + (size_t)nt * 16 * 256 + kt * 32);
            acc[nt] = __builtin_amdgcn_mfma_f32_16x16x32_bf16(af, bfr, acc[nt], 0, 0, 0);
        }
    }

    float ps[4] = {0.f, 0.f, 0.f, 0.f}, pq[4] = {0.f, 0.f, 0.f, 0.f};
    #pragma unroll
    for (int nt = 0; nt < 12; ++nt) {
        const int n = n0 + nt * 16 + r16;
        const float bv = b4[n];
        #pragma unroll
        for (int reg = 0; reg < 4; ++reg) {
            const int row = m0 + quad * 4 + reg;
            const float y = acc[nt][reg] + bv + x[(size_t)row * 768 + n];
            acc[nt][reg] = y;
            ps[reg] += y;
            pq[reg] += y * y;
        }
    }
    #pragma unroll
    for (int off = 1; off < 16; off <<= 1) {
        #pragma unroll
        for (int reg = 0; reg < 4; ++reg) {
            ps[reg] += __shfl_xor(ps[reg], off, 64);
            pq[reg] += __shfl_xor(pq[reg], off, 64);
        }
    }
    if (r16 == 0) {
        #pragma unroll
        for (int reg = 0; reg < 4; ++reg) {
            red[wv][quad * 4 + reg][0] = ps[reg];
            red[wv][quad * 4 + reg][1] = pq[reg];
        }
    }
    __syncthreads();
    if (tid < 16) {
        const float S = red[0][tid][0] + red[1][tid][0] + red[2][tid][0] + red[3][tid][0];
        const float Q = red[0][tid][1] + red[1][tid][1] + red[2][tid][1] + red[3][tid][1];
        const float mu = S * (1.0f / 768.0f);
        const float var = Q * (1.0f / 768.0f) - mu * mu;
        stats[tid][0] = mu;
        stats[tid][1] = rsqrtf(var + 1e-5f);
    }
    __syncthreads();

    float mu_r[4], rs_r[4];
    #pragma unroll
    for (int reg = 0; reg < 4; ++reg) {
        mu_r[reg] = stats[quad * 4 + reg][0];
        rs_r[reg] = stats[quad * 4 + reg][1];
    }
    #pragma unroll
    for (int nt = 0; nt < 12; ++nt) {
        const int n = n0 + nt * 16 + r16;
        const float g = gamma[n], bt = beta[n];
        #pragma unroll
        for (int reg = 0; reg < 4; ++reg) {
            const int row = m0 + quad * 4 + reg;
            out[(size_t)row * 768 + n] = g * (acc[nt][reg] - mu_r[reg]) * rs_r[reg] + bt;
        }
    }
}

extern "C" void kernel_launch(void* const* d_in, const int* in_sizes, int n_in,
                              void* d_out, int out_size, void* d_ws, size_t ws_size,
                              hipStream_t stream) {
    (void)n_in; (void)out_size; (void)ws_size;
    const float* x     = (const float*)d_in[0];
    const float* W1    = (const float*)d_in[1];
    const float* b1    = (const float*)d_in[2];
    const float* W2    = (const float*)d_in[3];
    const float* b2    = (const float*)d_in[4];
    const float* qw    = (const float*)d_in[5];
    const float* W3    = (const float*)d_in[6];
    const float* b3    = (const float*)d_in[7];
    const float* W4    = (const float*)d_in[8];
    const float* b4    = (const float*)d_in[9];
    const float* gamma = (const float*)d_in[10];
    const float* beta  = (const float*)d_in[11];
    float* out = (float*)d_out;

    const int D = 768, H = 256;
    const int B = in_sizes[0] / D;                       // 16384

    short* W1bt  = (short*)d_ws;                         // 256x768 bf16
    short* W4bt  = W1bt + (size_t)H * D;                 // 768x256 bf16
    short* W2T   = W4bt + (size_t)D * H;                 // 16x256 bf16
    float* Cg    = (float*)(W2T + 16 * 256);             // 16x8 f32
    float* feats = Cg + 128;                             // Bx8 f32
    short* ebt   = (short*)(feats + (size_t)B * 8);      // Bx256 bf16

    transpose_bf16_kernel<<<dim3(H / 32, D / 32), 256, 0, stream>>>(W1, W1bt, D, H);
    transpose_bf16_kernel<<<dim3(D / 32, H / 32), 256, 0, stream>>>(W4, W4bt, H, D);
    setup_kernel<<<1, 256, 0, stream>>>(qw, W2, Cg, W2T);
    gemm1_feats_kernel<<<dim3(B / 64), 512, 0, stream>>>(x, W1bt, b1, W2T, b2, feats, B);
    quantum_kernel<<<dim3(B / 4), 256, 0, stream>>>(feats, Cg, W3, b3, ebt);
    gemm4_ln_kernel<<<dim3(B / 16), 256, 0, stream>>>(ebt, W4bt, b4, x, gamma, beta, out, B);
}